// Round 4
// baseline (469.528 us; speedup 1.0000x reference)
//
#include <hip/hip_runtime.h>

// EarthSpecificBlock, MI355X round 4: qkv+mlp GEMMs barrier-free / LDS-free
// (fragments loaded directly from global; weights are L2-resident).
// qkv uses swapped operands (computes C^T) for sector-covering us4 stores.

#define QKV_PART 26542080   // 960*6*144*32 elements per q/k/v part

typedef __attribute__((ext_vector_type(8))) short bfrag;          // 8 bf16 (4 VGPR)
typedef __attribute__((ext_vector_type(4))) float f32x4;          // C/D frag
typedef __attribute__((ext_vector_type(4))) unsigned short us4;   // 8B of bf16

__device__ __forceinline__ unsigned short f2bf(float f) {
    unsigned int u = __builtin_bit_cast(unsigned int, f);
    u += 0x7fffu + ((u >> 16) & 1u);        // RNE
    return (unsigned short)(u >> 16);
}
__device__ __forceinline__ float bf2f(unsigned short s) {
    return __builtin_bit_cast(float, ((unsigned int)s) << 16);
}
__device__ __forceinline__ int token_of(int iw, int n) {
    int wi = iw % 15, hi = (iw / 15) % 16, zi = iw / 240;
    int ww = n % 12, hh = (n / 12) % 6, zz = n / 72;
    return ((zi * 2 + zz) * 96 + hi * 6 + hh) * 180 + wi * 12 + ww;
}

// ---- setup: transpose+convert w_qkv [192][576] -> [576][192] bf16 ----
__global__ __launch_bounds__(256) void wconv(const float* __restrict__ w_qkv,
                                             unsigned short* __restrict__ wt) {
    int id = blockIdx.x * 256 + threadIdx.x;       // 110592
    if (id >= 110592) return;
    int k = id / 576, c = id - k * 576;
    wt[c * 192 + k] = f2bf(w_qkv[id]);
}

// ---- setup: transpose+convert w (192x192) -> [n][k] bf16; y=0: w_proj, y=1: w_mlp ----
__global__ __launch_bounds__(256) void wconv2(const float* __restrict__ w_proj,
                                              const float* __restrict__ w_mlp,
                                              unsigned short* __restrict__ wp_t,
                                              unsigned short* __restrict__ wm_t) {
    int id = blockIdx.x * 256 + threadIdx.x;       // 36864
    if (id >= 36864) return;
    const float* src = blockIdx.y ? w_mlp : w_proj;
    unsigned short* dst = blockIdx.y ? wm_t : wp_t;
    int n = id / 192, k = id - n * 192;
    dst[id] = f2bf(src[(size_t)k * 192 + n]);
}

// ---- bias_r[th][i][j] = bias_table[posidx(i,j)][t][h] (bf16) ----
// Coalesced gather -> LDS transpose -> coalesced us4 writes (no sector waste).
__global__ __launch_bounds__(256) void bias_reorg(const float* __restrict__ bias_table,
                                                  unsigned short* __restrict__ bias_r) {
    __shared__ unsigned short T[384][68];          // 52224 B; row stride 136 B (8-aligned)
    int p0 = blockIdx.x * 64;                      // 324 blocks x 64 pairs
    int tid = threadIdx.x;
    for (int e = tid; e < 64 * 384; e += 256) {
        int pl = e / 384, th = e - pl * 384;
        int pair = p0 + pl;
        int i = pair / 144, j = pair - i * 144;
        int z1 = i / 72, h1 = (i / 12) % 6, w1 = i % 12;
        int z2 = j / 72, h2 = (j / 12) % 6, w2 = j % 12;
        int idx = (z1 + 2 * z2) * 828 + (h1 + 6 * h2) * 23 + (w1 - w2 + 11);
        T[th][pl] = f2bf(bias_table[(size_t)idx * 384 + th]);
    }
    __syncthreads();
    for (int e = tid; e < 384 * 16; e += 256) {
        int th = e >> 4, pc = e & 15;
        *(us4*)&bias_r[(size_t)th * 20736 + p0 + pc * 4] = *(const us4*)&T[th][pc * 4];
    }
}

// ---- QKV GEMM, swapped operands: D[c][t] = sum_k W[k][c] x[t][k]. ----
// No LDS, no barriers. Block = 64 tokens, 4 waves; wave w owns cols w*144..+143.
__global__ __launch_bounds__(256) void qkv_mfma(const float* __restrict__ x,
                                                const unsigned short* __restrict__ wt,
                                                const float* __restrict__ b_qkv,
                                                unsigned short* __restrict__ qkv_ws) {
    int tid = threadIdx.x;
    int m0 = blockIdx.x * 64;
    int w = tid >> 6, l = tid & 63, li = l & 15, lg = l >> 4;
    int nw0 = w * 144;

    f32x4 acc[9][4];
#pragma unroll
    for (int bn = 0; bn < 9; ++bn)
#pragma unroll
        for (int am = 0; am < 4; ++am) acc[bn][am] = (f32x4){0.f, 0.f, 0.f, 0.f};

    for (int kk = 0; kk < 6; ++kk) {
        int k0 = kk * 32 + lg * 8;
        bfrag af[9];                       // A = W^T chunk: lane li -> col c, 16B from wt[c][k]
#pragma unroll
        for (int bn = 0; bn < 9; ++bn)
            af[bn] = *(const bfrag*)&wt[(size_t)(nw0 + bn * 16 + li) * 192 + k0];
        bfrag xf[4];                       // B = x^T chunk: lane li -> token t, cvt f32->bf16
#pragma unroll
        for (int am = 0; am < 4; ++am) {
            const float* xp = &x[(size_t)(m0 + am * 16 + li) * 192 + k0];
            float4 v0 = *(const float4*)xp;
            float4 v1 = *(const float4*)(xp + 4);
            bfrag xb;
            xb[0] = (short)f2bf(v0.x); xb[1] = (short)f2bf(v0.y);
            xb[2] = (short)f2bf(v0.z); xb[3] = (short)f2bf(v0.w);
            xb[4] = (short)f2bf(v1.x); xb[5] = (short)f2bf(v1.y);
            xb[6] = (short)f2bf(v1.z); xb[7] = (short)f2bf(v1.w);
            xf[am] = xb;
        }
#pragma unroll
        for (int bn = 0; bn < 9; ++bn)
#pragma unroll
            for (int am = 0; am < 4; ++am)
                acc[bn][am] = __builtin_amdgcn_mfma_f32_16x16x32_bf16(af[bn], xf[am], acc[bn][am], 0, 0, 0);
    }

    // epilogue: lane holds D[c = nw0+bn*16+lg*4+r][t = m0+am*16+li]
    int base[4];
#pragma unroll
    for (int am = 0; am < 4; ++am) {
        int t = m0 + am * 16 + li;
        int z = t / 17280; int r1 = t - z * 17280;
        int hh_ = r1 / 180;  int ww_ = r1 - hh_ * 180;
        int zi = z >> 1, zz = z & 1;
        int hi = hh_ / 6, hs = hh_ - hi * 6;
        int wi = ww_ / 12, wsm = ww_ - wi * 12;
        int iw = (zi * 16 + hi) * 15 + wi;
        int n = (zz * 6 + hs) * 12 + wsm;
        base[am] = iw * 27648 + n * 32;
    }
#pragma unroll
    for (int bn = 0; bn < 9; ++bn) {
        int c0 = nw0 + bn * 16 + lg * 4;
        int p = c0 / 192;
        int rem = c0 - p * 192;
        int h = rem >> 5, d = rem & 31;
        float4 bq = *(const float4*)&b_qkv[c0];
        size_t off = (size_t)p * QKV_PART + h * 4608 + d;
#pragma unroll
        for (int am = 0; am < 4; ++am) {
            us4 o;
            o[0] = f2bf(acc[bn][am][0] + bq.x);
            o[1] = f2bf(acc[bn][am][1] + bq.y);
            o[2] = f2bf(acc[bn][am][2] + bq.z);
            o[3] = f2bf(acc[bn][am][3] + bq.w);
            *(us4*)&qkv_ws[off + base[am]] = o;
        }
    }
}

// ---- Attention: block=(iw,h), 3 waves x 3 query-tiles. S^T = mfma(K,Q). ----
__global__ __launch_bounds__(192) void attn_mfma(const unsigned short* __restrict__ qkv_ws,
                                                 const unsigned short* __restrict__ bias_r,
                                                 unsigned short* __restrict__ o_ws) {
    __shared__ __align__(16) unsigned short Kl[144 * 40];   // 11520 B
    __shared__ __align__(16) unsigned short Ql[144 * 40];   // 11520 B
    __shared__ __align__(16) unsigned short Vt[32 * 168];   // 10752 B (V^T, k-padded to 160)
    __shared__ __align__(16) unsigned short Pb[3][48 * 40]; // 11520 B per-wave P/O buf
    int tid = threadIdx.x;
    int iw = blockIdx.x, h = blockIdx.y;
    int w = tid >> 6, l = tid & 63, li = l & 15, lg = l >> 4;

    const unsigned short* qp = qkv_ws + (size_t)(iw * 6 + h) * 4608;
    const unsigned short* kp = qp + (size_t)QKV_PART;
    const unsigned short* vp = qp + 2 * (size_t)QKV_PART;

#pragma unroll
    for (int i = 0; i < 3; ++i) {
        int idx = tid + i * 192;                    // exactly 576
        int r = idx >> 2, g = idx & 3;
        *(uint4*)&Kl[r * 40 + g * 8] = *(const uint4*)&kp[r * 32 + g * 8];
        *(uint4*)&Ql[r * 40 + g * 8] = *(const uint4*)&qp[r * 32 + g * 8];
        uint4 v = *(const uint4*)&vp[r * 32 + g * 8];
        unsigned int vv[4] = {v.x, v.y, v.z, v.w};
#pragma unroll
        for (int e = 0; e < 4; ++e) {
            Vt[(g * 8 + 2 * e + 0) * 168 + r] = (unsigned short)(vv[e] & 0xffffu);
            Vt[(g * 8 + 2 * e + 1) * 168 + r] = (unsigned short)(vv[e] >> 16);
        }
    }
    if (tid < 64) {
        int d = tid >> 1, half = tid & 1;
        *(uint4*)&Vt[d * 168 + 144 + half * 8] = (uint4){0u, 0u, 0u, 0u};
    }
    __syncthreads();

    int it0 = w * 3;
    bfrag qf[3];
#pragma unroll
    for (int itl = 0; itl < 3; ++itl)
        qf[itl] = *(const bfrag*)&Ql[((it0 + itl) * 16 + li) * 40 + lg * 8];

    f32x4 S[9][3];
#pragma unroll
    for (int jt = 0; jt < 9; ++jt) {
        bfrag kf = *(const bfrag*)&Kl[(jt * 16 + li) * 40 + lg * 8];
#pragma unroll
        for (int itl = 0; itl < 3; ++itl) {
            f32x4 z = (f32x4){0.f, 0.f, 0.f, 0.f};
            S[jt][itl] = __builtin_amdgcn_mfma_f32_16x16x32_bf16(kf, qf[itl], z, 0, 0, 0);
        }
    }

    const unsigned short* bp = bias_r + ((size_t)((iw & 63) * 6 + h)) * 20736;
    const float inv_scale = 0.17677669529663687f;   // 1/sqrt(32)
#pragma unroll
    for (int jt = 0; jt < 9; ++jt) {
#pragma unroll
        for (int itl = 0; itl < 3; ++itl) {
            int i = (it0 + itl) * 16 + li;
            int j0 = jt * 16 + lg * 4;
            us4 bv = *(const us4*)&bp[i * 144 + j0];
#pragma unroll
            for (int r = 0; r < 4; ++r)
                S[jt][itl][r] = S[jt][itl][r] * inv_scale + bf2f(bv[r]);
        }
    }

    float inv[3];
#pragma unroll
    for (int itl = 0; itl < 3; ++itl) {
        float mx = -3.0e38f;
#pragma unroll
        for (int jt = 0; jt < 9; ++jt)
#pragma unroll
            for (int r = 0; r < 4; ++r) mx = fmaxf(mx, S[jt][itl][r]);
        mx = fmaxf(mx, __shfl_xor(mx, 16));
        mx = fmaxf(mx, __shfl_xor(mx, 32));
        float sum = 0.f;
#pragma unroll
        for (int jt = 0; jt < 9; ++jt)
#pragma unroll
            for (int r = 0; r < 4; ++r) {
                float e = __expf(S[jt][itl][r] - mx);
                S[jt][itl][r] = e;
                sum += e;
            }
        sum += __shfl_xor(sum, 16);
        sum += __shfl_xor(sum, 32);
        inv[itl] = 1.f / sum;
    }

    f32x4 O[2][3];
#pragma unroll
    for (int dt = 0; dt < 2; ++dt)
#pragma unroll
        for (int itl = 0; itl < 3; ++itl) O[dt][itl] = (f32x4){0.f, 0.f, 0.f, 0.f};

    for (int jc = 0; jc < 5; ++jc) {
#pragma unroll
        for (int itl = 0; itl < 3; ++itl) {
            int irow = itl * 16 + li;
#pragma unroll
            for (int half = 0; half < 2; ++half) {
                int jt = jc * 2 + half;
                us4 pk;
                if (jt < 9) {
                    pk[0] = f2bf(S[jt][itl][0]); pk[1] = f2bf(S[jt][itl][1]);
                    pk[2] = f2bf(S[jt][itl][2]); pk[3] = f2bf(S[jt][itl][3]);
                } else {
                    pk = (us4){0, 0, 0, 0};
                }
                *(us4*)&Pb[w][irow * 40 + half * 16 + lg * 4] = pk;
            }
        }
        bfrag pf[3], af[2];
#pragma unroll
        for (int itl = 0; itl < 3; ++itl)
            pf[itl] = *(const bfrag*)&Pb[w][(itl * 16 + li) * 40 + lg * 8];
#pragma unroll
        for (int dt = 0; dt < 2; ++dt)
            af[dt] = *(const bfrag*)&Vt[(dt * 16 + li) * 168 + jc * 32 + lg * 8];
#pragma unroll
        for (int dt = 0; dt < 2; ++dt)
#pragma unroll
            for (int itl = 0; itl < 3; ++itl)
                O[dt][itl] = __builtin_amdgcn_mfma_f32_16x16x32_bf16(af[dt], pf[itl], O[dt][itl], 0, 0, 0);
    }

#pragma unroll
    for (int itl = 0; itl < 3; ++itl) {
#pragma unroll
        for (int dt = 0; dt < 2; ++dt) {
            us4 ov;
            ov[0] = f2bf(O[dt][itl][0] * inv[itl]);
            ov[1] = f2bf(O[dt][itl][1] * inv[itl]);
            ov[2] = f2bf(O[dt][itl][2] * inv[itl]);
            ov[3] = f2bf(O[dt][itl][3] * inv[itl]);
            *(us4*)&Pb[w][(itl * 16 + li) * 40 + dt * 16 + lg * 4] = ov;
        }
    }
#pragma unroll
    for (int s = 0; s < 3; ++s) {
        int gi = s * 64 + l;
        int row = gi >> 2, g = gi & 3;
        uint4 v = *(const uint4*)&Pb[w][row * 40 + g * 8];
        int t = token_of(iw, it0 * 16 + row);
        *(uint4*)&o_ws[(size_t)t * 192 + h * 32 + g * 8] = v;
    }
}

// ---- Fused proj+LN1+res -> mlp+LN2+res. 64 rows/block; frag loads direct from
// global (weights L2-resident); LDS only for the x1 round-trip. 1 barrier. ----
__global__ __launch_bounds__(256) void mlp_mfma(const unsigned short* __restrict__ o_ws,
                                                const float* __restrict__ x,
                                                const unsigned short* __restrict__ wp_t,
                                                const float* __restrict__ b_proj,
                                                const float* __restrict__ g1,
                                                const float* __restrict__ b1,
                                                const float* __restrict__ g2,
                                                const float* __restrict__ b2,
                                                const unsigned short* __restrict__ wm_t,
                                                const float* __restrict__ b_mlp,
                                                float* __restrict__ out) {
    __shared__ __align__(16) unsigned short Al[64 * 200];   // 25600 B (x1 bf16)
    int tid = threadIdx.x;
    int t0 = blockIdx.x * 64;
    int w = tid >> 6, l = tid & 63, li = l & 15, lg = l >> 4;
    int trow = t0 + w * 16 + li;

    // GEMM1: o @ w_proj
    f32x4 C[12];
#pragma unroll
    for (int nt = 0; nt < 12; ++nt) C[nt] = (f32x4){0.f, 0.f, 0.f, 0.f};
    for (int kk = 0; kk < 6; ++kk) {
        int k0 = kk * 32 + lg * 8;
        bfrag ao = *(const bfrag*)&o_ws[(size_t)trow * 192 + k0];
        bfrag bw[12];
#pragma unroll
        for (int nt = 0; nt < 12; ++nt)
            bw[nt] = *(const bfrag*)&wp_t[(size_t)(nt * 16 + li) * 192 + k0];
#pragma unroll
        for (int nt = 0; nt < 12; ++nt)
            C[nt] = __builtin_amdgcn_mfma_f32_16x16x32_bf16(ao, bw[nt], C[nt], 0, 0, 0);
    }

    // LN1 + residual; C := x1 (f32); write bf16 x1 into Al (own wave's rows)
    {
        float bp[12], gg[12], bb[12];
#pragma unroll
        for (int nt = 0; nt < 12; ++nt) {
            int f = nt * 16 + li;
            bp[nt] = b_proj[f]; gg[nt] = g1[f]; bb[nt] = b1[f];
        }
#pragma unroll
        for (int r = 0; r < 4; ++r) {
            float s1 = 0.f;
#pragma unroll
            for (int nt = 0; nt < 12; ++nt) s1 += C[nt][r] + bp[nt];
            s1 += __shfl_xor(s1, 1); s1 += __shfl_xor(s1, 2);
            s1 += __shfl_xor(s1, 4); s1 += __shfl_xor(s1, 8);
            float mean = s1 * (1.f / 192.f);
            float s2 = 0.f;
#pragma unroll
            for (int nt = 0; nt < 12; ++nt) {
                float dv = C[nt][r] + bp[nt] - mean; s2 += dv * dv;
            }
            s2 += __shfl_xor(s2, 1); s2 += __shfl_xor(s2, 2);
            s2 += __shfl_xor(s2, 4); s2 += __shfl_xor(s2, 8);
            float rstd = rsqrtf(s2 * (1.f / 192.f) + 1e-5f);
            int row = w * 16 + lg * 4 + r;
            int t = t0 + row;
#pragma unroll
            for (int nt = 0; nt < 12; ++nt) {
                int f = nt * 16 + li;
                float ln = (C[nt][r] + bp[nt] - mean) * rstd * gg[nt] + bb[nt];
                float x1 = x[(size_t)t * 192 + f] + ln;
                C[nt][r] = x1;
                Al[row * 200 + f] = f2bf(x1);
            }
        }
    }
    __syncthreads();

    // GEMM2: x1 @ w_mlp
    f32x4 C2[12];
#pragma unroll
    for (int nt = 0; nt < 12; ++nt) C2[nt] = (f32x4){0.f, 0.f, 0.f, 0.f};
    for (int kk = 0; kk < 6; ++kk) {
        int k0 = kk * 32 + lg * 8;
        bfrag a2 = *(const bfrag*)&Al[(w * 16 + li) * 200 + k0];
        bfrag bw[12];
#pragma unroll
        for (int nt = 0; nt < 12; ++nt)
            bw[nt] = *(const bfrag*)&wm_t[(size_t)(nt * 16 + li) * 192 + k0];
#pragma unroll
        for (int nt = 0; nt < 12; ++nt)
            C2[nt] = __builtin_amdgcn_mfma_f32_16x16x32_bf16(a2, bw[nt], C2[nt], 0, 0, 0);
    }

    // LN2 + residual -> out (fp32)
    {
        float bp[12], gg[12], bb[12];
#pragma unroll
        for (int nt = 0; nt < 12; ++nt) {
            int f = nt * 16 + li;
            bp[nt] = b_mlp[f]; gg[nt] = g2[f]; bb[nt] = b2[f];
        }
#pragma unroll
        for (int r = 0; r < 4; ++r) {
            float s1 = 0.f;
#pragma unroll
            for (int nt = 0; nt < 12; ++nt) s1 += C2[nt][r] + bp[nt];
            s1 += __shfl_xor(s1, 1); s1 += __shfl_xor(s1, 2);
            s1 += __shfl_xor(s1, 4); s1 += __shfl_xor(s1, 8);
            float mean = s1 * (1.f / 192.f);
            float s2 = 0.f;
#pragma unroll
            for (int nt = 0; nt < 12; ++nt) {
                float dv = C2[nt][r] + bp[nt] - mean; s2 += dv * dv;
            }
            s2 += __shfl_xor(s2, 1); s2 += __shfl_xor(s2, 2);
            s2 += __shfl_xor(s2, 4); s2 += __shfl_xor(s2, 8);
            float rstd = rsqrtf(s2 * (1.f / 192.f) + 1e-5f);
            int t = t0 + w * 16 + lg * 4 + r;
#pragma unroll
            for (int nt = 0; nt < 12; ++nt) {
                int f = nt * 16 + li;
                float ln = (C2[nt][r] + bp[nt] - mean) * rstd * gg[nt] + bb[nt];
                out[(size_t)t * 192 + f] = C[nt][r] + ln;
            }
        }
    }
}

extern "C" void kernel_launch(void* const* d_in, const int* in_sizes, int n_in,
                              void* d_out, int out_size, void* d_ws, size_t ws_size,
                              hipStream_t stream) {
    const float* x          = (const float*)d_in[0];
    const float* w_qkv      = (const float*)d_in[1];
    const float* b_qkv      = (const float*)d_in[2];
    const float* w_proj     = (const float*)d_in[3];
    const float* b_proj     = (const float*)d_in[4];
    const float* bias_table = (const float*)d_in[5];
    const float* g1         = (const float*)d_in[6];
    const float* b1         = (const float*)d_in[7];
    const float* g2         = (const float*)d_in[8];
    const float* b2         = (const float*)d_in[9];
    const float* w_mlp      = (const float*)d_in[10];
    const float* b_mlp      = (const float*)d_in[11];

    char* ws = (char*)d_ws;
    unsigned short* qkv_ws = (unsigned short*)ws;                   // 159,252,480 B
    unsigned short* bias_r = (unsigned short*)(ws + 159252480);     //  15,925,248 B
    unsigned short* o_ws   = (unsigned short*)(ws + 175177728);     //  53,084,160 B
    // w_qkv_t overlaps o_ws: consumed by qkv_mfma before attn writes o_ws.
    unsigned short* w_t    = o_ws;                                  //     221,184 B
    // wp_t/wm_t overlap qkv_ws: written AFTER attn (stream order), read by mlp.
    unsigned short* wp_t   = qkv_ws;                                //     147,456 B
    unsigned short* wm_t   = qkv_ws + 73728;                        //     147,456 B

    wconv<<<432, 256, 0, stream>>>(w_qkv, w_t);
    bias_reorg<<<324, 256, 0, stream>>>(bias_table, bias_r);
    qkv_mfma<<<2160, 256, 0, stream>>>(x, w_t, b_qkv, qkv_ws);
    attn_mfma<<<dim3(960, 6), 192, 0, stream>>>(qkv_ws, bias_r, o_ws);
    wconv2<<<dim3(144, 2), 256, 0, stream>>>(w_proj, w_mlp, wp_t, wm_t);
    mlp_mfma<<<2160, 256, 0, stream>>>(o_ws, x, wp_t, b_proj, g1, b1, g2, b2,
                                       wm_t, b_mlp, (float*)d_out);
}

// Round 5
// 394.072 us; speedup vs baseline: 1.1915x; 1.1915x over previous
//
#include <hip/hip_runtime.h>

// EarthSpecificBlock, MI355X round 5:
//  - mlp reverted to round-3 LDS-staged weights (round-4 direct-global regressed)
//  - x pre-converted to bf16 (xconv) -> qkv loses all f2bf VALU + half its fetch
//  - attn: Pb aliased onto Ql (own-wave rows) -> LDS 46->34.6 KB, occupancy up

#define QKV_PART 26542080   // 960*6*144*32 elements per q/k/v part

typedef __attribute__((ext_vector_type(8))) short bfrag;          // 8 bf16 (4 VGPR)
typedef __attribute__((ext_vector_type(4))) float f32x4;          // C/D frag
typedef __attribute__((ext_vector_type(4))) unsigned short us4;   // 8B of bf16
typedef __attribute__((ext_vector_type(8))) unsigned short us8;   // 16B of bf16

__device__ __forceinline__ unsigned short f2bf(float f) {
    unsigned int u = __builtin_bit_cast(unsigned int, f);
    u += 0x7fffu + ((u >> 16) & 1u);        // RNE
    return (unsigned short)(u >> 16);
}
__device__ __forceinline__ float bf2f(unsigned short s) {
    return __builtin_bit_cast(float, ((unsigned int)s) << 16);
}
__device__ __forceinline__ int token_of(int iw, int n) {
    int wi = iw % 15, hi = (iw / 15) % 16, zi = iw / 240;
    int ww = n % 12, hh = (n / 12) % 6, zz = n / 72;
    return ((zi * 2 + zz) * 96 + hi * 6 + hh) * 180 + wi * 12 + ww;
}

// ---- setup: transpose+convert w_qkv [192][576] -> [576][192] bf16 ----
__global__ __launch_bounds__(256) void wconv(const float* __restrict__ w_qkv,
                                             unsigned short* __restrict__ wt) {
    int id = blockIdx.x * 256 + threadIdx.x;       // 110592
    if (id >= 110592) return;
    int k = id / 576, c = id - k * 576;
    wt[c * 192 + k] = f2bf(w_qkv[id]);
}

// ---- setup: x fp32 -> bf16 (one pass; removes per-use cvt from qkv) ----
__global__ __launch_bounds__(256) void xconv(const float* __restrict__ x,
                                             unsigned short* __restrict__ x_bf) {
    int id = blockIdx.x * 256 + threadIdx.x;       // 3,317,760 (x8 elems)
    if (id >= 3317760) return;
    const float* xp = x + (size_t)id * 8;
    float4 v0 = *(const float4*)xp;
    float4 v1 = *(const float4*)(xp + 4);
    us8 o;
    o[0] = f2bf(v0.x); o[1] = f2bf(v0.y); o[2] = f2bf(v0.z); o[3] = f2bf(v0.w);
    o[4] = f2bf(v1.x); o[5] = f2bf(v1.y); o[6] = f2bf(v1.z); o[7] = f2bf(v1.w);
    *(us8*)&x_bf[(size_t)id * 8] = o;
}

// ---- setup: transpose+convert w (192x192) -> [n][k] bf16; y=0: w_proj, y=1: w_mlp ----
__global__ __launch_bounds__(256) void wconv2(const float* __restrict__ w_proj,
                                              const float* __restrict__ w_mlp,
                                              unsigned short* __restrict__ wp_t,
                                              unsigned short* __restrict__ wm_t) {
    int id = blockIdx.x * 256 + threadIdx.x;       // 36864
    if (id >= 36864) return;
    const float* src = blockIdx.y ? w_mlp : w_proj;
    unsigned short* dst = blockIdx.y ? wm_t : wp_t;
    int n = id / 192, k = id - n * 192;
    dst[id] = f2bf(src[(size_t)k * 192 + n]);
}

// ---- bias_r[th][i][j] = bias_table[posidx(i,j)][t][h] (bf16) ----
__global__ __launch_bounds__(256) void bias_reorg(const float* __restrict__ bias_table,
                                                  unsigned short* __restrict__ bias_r) {
    __shared__ unsigned short T[384][68];
    int p0 = blockIdx.x * 64;                      // 324 blocks x 64 pairs
    int tid = threadIdx.x;
    for (int e = tid; e < 64 * 384; e += 256) {
        int pl = e / 384, th = e - pl * 384;
        int pair = p0 + pl;
        int i = pair / 144, j = pair - i * 144;
        int z1 = i / 72, h1 = (i / 12) % 6, w1 = i % 12;
        int z2 = j / 72, h2 = (j / 12) % 6, w2 = j % 12;
        int idx = (z1 + 2 * z2) * 828 + (h1 + 6 * h2) * 23 + (w1 - w2 + 11);
        T[th][pl] = f2bf(bias_table[(size_t)idx * 384 + th]);
    }
    __syncthreads();
    for (int e = tid; e < 384 * 16; e += 256) {
        int th = e >> 4, pc = e & 15;
        *(us4*)&bias_r[(size_t)th * 20736 + p0 + pc * 4] = *(const us4*)&T[th][pc * 4];
    }
}

// ---- QKV GEMM, swapped operands: D[c][t] = sum_k W[k][c] x[t][k]. ----
// No LDS, no barriers; x already bf16 -> pure bfrag loads, zero cvt VALU.
__global__ __launch_bounds__(256) void qkv_mfma(const unsigned short* __restrict__ x_bf,
                                                const unsigned short* __restrict__ wt,
                                                const float* __restrict__ b_qkv,
                                                unsigned short* __restrict__ qkv_ws) {
    int tid = threadIdx.x;
    int m0 = blockIdx.x * 64;
    int w = tid >> 6, l = tid & 63, li = l & 15, lg = l >> 4;
    int nw0 = w * 144;

    f32x4 acc[9][4];
#pragma unroll
    for (int bn = 0; bn < 9; ++bn)
#pragma unroll
        for (int am = 0; am < 4; ++am) acc[bn][am] = (f32x4){0.f, 0.f, 0.f, 0.f};

    for (int kk = 0; kk < 6; ++kk) {
        int k0 = kk * 32 + lg * 8;
        bfrag af[9];
#pragma unroll
        for (int bn = 0; bn < 9; ++bn)
            af[bn] = *(const bfrag*)&wt[(size_t)(nw0 + bn * 16 + li) * 192 + k0];
        bfrag xf[4];
#pragma unroll
        for (int am = 0; am < 4; ++am)
            xf[am] = *(const bfrag*)&x_bf[(size_t)(m0 + am * 16 + li) * 192 + k0];
#pragma unroll
        for (int bn = 0; bn < 9; ++bn)
#pragma unroll
            for (int am = 0; am < 4; ++am)
                acc[bn][am] = __builtin_amdgcn_mfma_f32_16x16x32_bf16(af[bn], xf[am], acc[bn][am], 0, 0, 0);
    }

    int base[4];
#pragma unroll
    for (int am = 0; am < 4; ++am) {
        int t = m0 + am * 16 + li;
        int z = t / 17280; int r1 = t - z * 17280;
        int hh_ = r1 / 180;  int ww_ = r1 - hh_ * 180;
        int zi = z >> 1, zz = z & 1;
        int hi = hh_ / 6, hs = hh_ - hi * 6;
        int wi = ww_ / 12, wsm = ww_ - wi * 12;
        int iw = (zi * 16 + hi) * 15 + wi;
        int n = (zz * 6 + hs) * 12 + wsm;
        base[am] = iw * 27648 + n * 32;
    }
#pragma unroll
    for (int bn = 0; bn < 9; ++bn) {
        int c0 = nw0 + bn * 16 + lg * 4;
        int p = c0 / 192;
        int rem = c0 - p * 192;
        int h = rem >> 5, d = rem & 31;
        float4 bq = *(const float4*)&b_qkv[c0];
        size_t off = (size_t)p * QKV_PART + h * 4608 + d;
#pragma unroll
        for (int am = 0; am < 4; ++am) {
            us4 o;
            o[0] = f2bf(acc[bn][am][0] + bq.x);
            o[1] = f2bf(acc[bn][am][1] + bq.y);
            o[2] = f2bf(acc[bn][am][2] + bq.z);
            o[3] = f2bf(acc[bn][am][3] + bq.w);
            *(us4*)&qkv_ws[off + base[am]] = o;
        }
    }
}

// ---- Attention: block=(iw,h), 3 waves x 3 query-tiles. S^T = mfma(K,Q). ----
// Pb aliased onto Ql: wave w's P/O staging = its OWN 48 Q-rows (read-complete
// into qf regs before first write; no other wave reads those rows).
__global__ __launch_bounds__(192) void attn_mfma(const unsigned short* __restrict__ qkv_ws,
                                                 const unsigned short* __restrict__ bias_r,
                                                 unsigned short* __restrict__ o_ws) {
    __shared__ __align__(16) unsigned short Kl[144 * 40];   // 11520 B
    __shared__ __align__(16) unsigned short Ql[144 * 40];   // 11520 B (+ aliased Pb)
    __shared__ __align__(16) unsigned short Vt[32 * 168];   // 10752 B (V^T, k-pad to 160)
    int tid = threadIdx.x;
    int iw = blockIdx.x, h = blockIdx.y;
    int w = tid >> 6, l = tid & 63, li = l & 15, lg = l >> 4;

    const unsigned short* qp = qkv_ws + (size_t)(iw * 6 + h) * 4608;
    const unsigned short* kp = qp + (size_t)QKV_PART;
    const unsigned short* vp = qp + 2 * (size_t)QKV_PART;

#pragma unroll
    for (int i = 0; i < 3; ++i) {
        int idx = tid + i * 192;                    // exactly 576
        int r = idx >> 2, g = idx & 3;
        *(uint4*)&Kl[r * 40 + g * 8] = *(const uint4*)&kp[r * 32 + g * 8];
        *(uint4*)&Ql[r * 40 + g * 8] = *(const uint4*)&qp[r * 32 + g * 8];
        uint4 v = *(const uint4*)&vp[r * 32 + g * 8];
        unsigned int vv[4] = {v.x, v.y, v.z, v.w};
#pragma unroll
        for (int e = 0; e < 4; ++e) {
            Vt[(g * 8 + 2 * e + 0) * 168 + r] = (unsigned short)(vv[e] & 0xffffu);
            Vt[(g * 8 + 2 * e + 1) * 168 + r] = (unsigned short)(vv[e] >> 16);
        }
    }
    if (tid < 64) {
        int d = tid >> 1, half = tid & 1;
        *(uint4*)&Vt[d * 168 + 144 + half * 8] = (uint4){0u, 0u, 0u, 0u};
    }
    __syncthreads();

    int it0 = w * 3;
    unsigned short* Pbw = &Ql[(size_t)w * 48 * 40];   // alias: own wave's Q rows
    bfrag qf[3];
#pragma unroll
    for (int itl = 0; itl < 3; ++itl)
        qf[itl] = *(const bfrag*)&Ql[((it0 + itl) * 16 + li) * 40 + lg * 8];

    f32x4 S[9][3];
#pragma unroll
    for (int jt = 0; jt < 9; ++jt) {
        bfrag kf = *(const bfrag*)&Kl[(jt * 16 + li) * 40 + lg * 8];
#pragma unroll
        for (int itl = 0; itl < 3; ++itl) {
            f32x4 z = (f32x4){0.f, 0.f, 0.f, 0.f};
            S[jt][itl] = __builtin_amdgcn_mfma_f32_16x16x32_bf16(kf, qf[itl], z, 0, 0, 0);
        }
    }

    const unsigned short* bp = bias_r + ((size_t)((iw & 63) * 6 + h)) * 20736;
    const float inv_scale = 0.17677669529663687f;   // 1/sqrt(32)
#pragma unroll
    for (int jt = 0; jt < 9; ++jt) {
#pragma unroll
        for (int itl = 0; itl < 3; ++itl) {
            int i = (it0 + itl) * 16 + li;
            int j0 = jt * 16 + lg * 4;
            us4 bv = *(const us4*)&bp[i * 144 + j0];
#pragma unroll
            for (int r = 0; r < 4; ++r)
                S[jt][itl][r] = S[jt][itl][r] * inv_scale + bf2f(bv[r]);
        }
    }

    float inv[3];
#pragma unroll
    for (int itl = 0; itl < 3; ++itl) {
        float mx = -3.0e38f;
#pragma unroll
        for (int jt = 0; jt < 9; ++jt)
#pragma unroll
            for (int r = 0; r < 4; ++r) mx = fmaxf(mx, S[jt][itl][r]);
        mx = fmaxf(mx, __shfl_xor(mx, 16));
        mx = fmaxf(mx, __shfl_xor(mx, 32));
        float sum = 0.f;
#pragma unroll
        for (int jt = 0; jt < 9; ++jt)
#pragma unroll
            for (int r = 0; r < 4; ++r) {
                float e = __expf(S[jt][itl][r] - mx);
                S[jt][itl][r] = e;
                sum += e;
            }
        sum += __shfl_xor(sum, 16);
        sum += __shfl_xor(sum, 32);
        inv[itl] = 1.f / sum;
    }

    f32x4 O[2][3];
#pragma unroll
    for (int dt = 0; dt < 2; ++dt)
#pragma unroll
        for (int itl = 0; itl < 3; ++itl) O[dt][itl] = (f32x4){0.f, 0.f, 0.f, 0.f};

    for (int jc = 0; jc < 5; ++jc) {
#pragma unroll
        for (int itl = 0; itl < 3; ++itl) {
            int irow = itl * 16 + li;
#pragma unroll
            for (int half = 0; half < 2; ++half) {
                int jt = jc * 2 + half;
                us4 pk;
                if (jt < 9) {
                    pk[0] = f2bf(S[jt][itl][0]); pk[1] = f2bf(S[jt][itl][1]);
                    pk[2] = f2bf(S[jt][itl][2]); pk[3] = f2bf(S[jt][itl][3]);
                } else {
                    pk = (us4){0, 0, 0, 0};
                }
                *(us4*)&Pbw[irow * 40 + half * 16 + lg * 4] = pk;
            }
        }
        bfrag pf[3], af[2];
#pragma unroll
        for (int itl = 0; itl < 3; ++itl)
            pf[itl] = *(const bfrag*)&Pbw[(itl * 16 + li) * 40 + lg * 8];
#pragma unroll
        for (int dt = 0; dt < 2; ++dt)
            af[dt] = *(const bfrag*)&Vt[(dt * 16 + li) * 168 + jc * 32 + lg * 8];
#pragma unroll
        for (int dt = 0; dt < 2; ++dt)
#pragma unroll
            for (int itl = 0; itl < 3; ++itl)
                O[dt][itl] = __builtin_amdgcn_mfma_f32_16x16x32_bf16(af[dt], pf[itl], O[dt][itl], 0, 0, 0);
    }

#pragma unroll
    for (int itl = 0; itl < 3; ++itl) {
#pragma unroll
        for (int dt = 0; dt < 2; ++dt) {
            us4 ov;
            ov[0] = f2bf(O[dt][itl][0] * inv[itl]);
            ov[1] = f2bf(O[dt][itl][1] * inv[itl]);
            ov[2] = f2bf(O[dt][itl][2] * inv[itl]);
            ov[3] = f2bf(O[dt][itl][3] * inv[itl]);
            *(us4*)&Pbw[(itl * 16 + li) * 40 + dt * 16 + lg * 4] = ov;
        }
    }
#pragma unroll
    for (int s = 0; s < 3; ++s) {
        int gi = s * 64 + l;
        int row = gi >> 2, g = gi & 3;
        uint4 v = *(const uint4*)&Pbw[row * 40 + g * 8];
        int t = token_of(iw, it0 * 16 + row);
        *(uint4*)&o_ws[(size_t)t * 192 + h * 32 + g * 8] = v;
    }
}

// ---- Fused proj+LN1+res -> mlp+LN2+res. 64 rows/block, LDS-staged weights
// (round-3 proven version). ----
__global__ __launch_bounds__(256) void mlp_mfma(const unsigned short* __restrict__ o_ws,
                                                const float* __restrict__ x,
                                                const unsigned short* __restrict__ wp_t,
                                                const float* __restrict__ b_proj,
                                                const float* __restrict__ g1,
                                                const float* __restrict__ b1,
                                                const float* __restrict__ g2,
                                                const float* __restrict__ b2,
                                                const unsigned short* __restrict__ wm_t,
                                                const float* __restrict__ b_mlp,
                                                float* __restrict__ out) {
    __shared__ __align__(16) unsigned short Al[64 * 200];   // 25600 B (A1 then x1)
    __shared__ __align__(16) unsigned short Bl[192 * 40];   // 15360 B
    int tid = threadIdx.x;
    int t0 = blockIdx.x * 64;
    int w = tid >> 6, l = tid & 63, li = l & 15, lg = l >> 4;

#pragma unroll
    for (int i = 0; i < 6; ++i) {
        int idx = tid + i * 256;                 // < 1536
        int r = idx / 24, g = idx - r * 24;
        *(uint4*)&Al[r * 200 + g * 8] = *(const uint4*)&o_ws[(size_t)(t0 + r) * 192 + g * 8];
    }
    __syncthreads();

    f32x4 C[12];
#pragma unroll
    for (int nt = 0; nt < 12; ++nt) C[nt] = (f32x4){0.f, 0.f, 0.f, 0.f};
    for (int kk = 0; kk < 6; ++kk) {
        __syncthreads();
#pragma unroll
        for (int i = 0; i < 3; ++i) {
            int idx = tid + i * 256;             // < 768
            int r = idx >> 2, g = idx & 3;
            *(uint4*)&Bl[r * 40 + g * 8] = *(const uint4*)&wp_t[(size_t)r * 192 + kk * 32 + g * 8];
        }
        __syncthreads();
        bfrag a = *(const bfrag*)&Al[(w * 16 + li) * 200 + kk * 32 + lg * 8];
#pragma unroll
        for (int nt = 0; nt < 12; ++nt) {
            bfrag b = *(const bfrag*)&Bl[(nt * 16 + li) * 40 + lg * 8];
            C[nt] = __builtin_amdgcn_mfma_f32_16x16x32_bf16(a, b, C[nt], 0, 0, 0);
        }
    }

    // LN1 + residual; C := x1 (f32); write bf16 x1 into Al (own rows only)
    {
        float bp[12], gg[12], bb[12];
#pragma unroll
        for (int nt = 0; nt < 12; ++nt) {
            int f = nt * 16 + li;
            bp[nt] = b_proj[f]; gg[nt] = g1[f]; bb[nt] = b1[f];
        }
#pragma unroll
        for (int r = 0; r < 4; ++r) {
            float s1 = 0.f;
#pragma unroll
            for (int nt = 0; nt < 12; ++nt) s1 += C[nt][r] + bp[nt];
            s1 += __shfl_xor(s1, 1); s1 += __shfl_xor(s1, 2);
            s1 += __shfl_xor(s1, 4); s1 += __shfl_xor(s1, 8);
            float mean = s1 * (1.f / 192.f);
            float s2 = 0.f;
#pragma unroll
            for (int nt = 0; nt < 12; ++nt) {
                float dv = C[nt][r] + bp[nt] - mean; s2 += dv * dv;
            }
            s2 += __shfl_xor(s2, 1); s2 += __shfl_xor(s2, 2);
            s2 += __shfl_xor(s2, 4); s2 += __shfl_xor(s2, 8);
            float rstd = rsqrtf(s2 * (1.f / 192.f) + 1e-5f);
            int row = w * 16 + lg * 4 + r;
            int t = t0 + row;
#pragma unroll
            for (int nt = 0; nt < 12; ++nt) {
                int f = nt * 16 + li;
                float ln = (C[nt][r] + bp[nt] - mean) * rstd * gg[nt] + bb[nt];
                float x1 = x[(size_t)t * 192 + f] + ln;
                C[nt][r] = x1;
                Al[row * 200 + f] = f2bf(x1);
            }
        }
    }

    f32x4 C2[12];
#pragma unroll
    for (int nt = 0; nt < 12; ++nt) C2[nt] = (f32x4){0.f, 0.f, 0.f, 0.f};
    for (int kk = 0; kk < 6; ++kk) {
        __syncthreads();
#pragma unroll
        for (int i = 0; i < 3; ++i) {
            int idx = tid + i * 256;             // < 768
            int r = idx >> 2, g = idx & 3;
            *(uint4*)&Bl[r * 40 + g * 8] = *(const uint4*)&wm_t[(size_t)r * 192 + kk * 32 + g * 8];
        }
        __syncthreads();
        bfrag a = *(const bfrag*)&Al[(w * 16 + li) * 200 + kk * 32 + lg * 8];
#pragma unroll
        for (int nt = 0; nt < 12; ++nt) {
            bfrag b = *(const bfrag*)&Bl[(nt * 16 + li) * 40 + lg * 8];
            C2[nt] = __builtin_amdgcn_mfma_f32_16x16x32_bf16(a, b, C2[nt], 0, 0, 0);
        }
    }

    // LN2 + residual -> out (fp32)
    {
        float bp[12], gg[12], bb[12];
#pragma unroll
        for (int nt = 0; nt < 12; ++nt) {
            int f = nt * 16 + li;
            bp[nt] = b_mlp[f]; gg[nt] = g2[f]; bb[nt] = b2[f];
        }
#pragma unroll
        for (int r = 0; r < 4; ++r) {
            float s1 = 0.f;
#pragma unroll
            for (int nt = 0; nt < 12; ++nt) s1 += C2[nt][r] + bp[nt];
            s1 += __shfl_xor(s1, 1); s1 += __shfl_xor(s1, 2);
            s1 += __shfl_xor(s1, 4); s1 += __shfl_xor(s1, 8);
            float mean = s1 * (1.f / 192.f);
            float s2 = 0.f;
#pragma unroll
            for (int nt = 0; nt < 12; ++nt) {
                float dv = C2[nt][r] + bp[nt] - mean; s2 += dv * dv;
            }
            s2 += __shfl_xor(s2, 1); s2 += __shfl_xor(s2, 2);
            s2 += __shfl_xor(s2, 4); s2 += __shfl_xor(s2, 8);
            float rstd = rsqrtf(s2 * (1.f / 192.f) + 1e-5f);
            int t = t0 + w * 16 + lg * 4 + r;
#pragma unroll
            for (int nt = 0; nt < 12; ++nt) {
                int f = nt * 16 + li;
                float ln = (C2[nt][r] + bp[nt] - mean) * rstd * gg[nt] + bb[nt];
                out[(size_t)t * 192 + f] = C[nt][r] + ln;
            }
        }
    }
}

extern "C" void kernel_launch(void* const* d_in, const int* in_sizes, int n_in,
                              void* d_out, int out_size, void* d_ws, size_t ws_size,
                              hipStream_t stream) {
    const float* x          = (const float*)d_in[0];
    const float* w_qkv      = (const float*)d_in[1];
    const float* b_qkv      = (const float*)d_in[2];
    const float* w_proj     = (const float*)d_in[3];
    const float* b_proj     = (const float*)d_in[4];
    const float* bias_table = (const float*)d_in[5];
    const float* g1         = (const float*)d_in[6];
    const float* b1         = (const float*)d_in[7];
    const float* g2         = (const float*)d_in[8];
    const float* b2         = (const float*)d_in[9];
    const float* w_mlp      = (const float*)d_in[10];
    const float* b_mlp      = (const float*)d_in[11];

    char* ws = (char*)d_ws;
    unsigned short* qkv_ws = (unsigned short*)ws;                   // 159,252,480 B
    unsigned short* bias_r = (unsigned short*)(ws + 159252480);     //  15,925,248 B
    unsigned short* o_ws   = (unsigned short*)(ws + 175177728);     //  53,084,160 B
    // Overlays (all checked against stream order):
    //  w_t  @ bias_r : written by wconv, read by qkv, clobbered by bias_reorg (after qkv)
    //  x_bf @ o_ws   : written by xconv, read by qkv, clobbered by attn (after qkv)
    //  wp_t/wm_t @ qkv_ws : written by wconv2 (after attn), read by mlp
    unsigned short* w_t    = bias_r;                                //     221,184 B
    unsigned short* x_bf   = o_ws;                                  //  53,084,160 B
    unsigned short* wp_t   = qkv_ws;                                //     147,456 B
    unsigned short* wm_t   = qkv_ws + 73728;                        //     147,456 B

    wconv<<<432, 256, 0, stream>>>(w_qkv, w_t);
    xconv<<<12960, 256, 0, stream>>>(x, x_bf);
    qkv_mfma<<<2160, 256, 0, stream>>>(x_bf, w_t, b_qkv, qkv_ws);
    bias_reorg<<<324, 256, 0, stream>>>(bias_table, bias_r);
    attn_mfma<<<dim3(960, 6), 192, 0, stream>>>(qkv_ws, bias_r, o_ws);
    wconv2<<<dim3(144, 2), 256, 0, stream>>>(w_proj, w_mlp, wp_t, wm_t);
    mlp_mfma<<<2160, 256, 0, stream>>>(o_ws, x, wp_t, b_proj, g1, b1, g2, b2,
                                       wm_t, b_mlp, (float*)d_out);
}

// Round 6
// 347.271 us; speedup vs baseline: 1.3521x; 1.1348x over previous
//
#include <hip/hip_runtime.h>

// EarthSpecificBlock, MI355X round 6:
//  - mlp restructured: full weight matrix staged ONCE per GEMM in LDS (72 KB),
//    GEMM1 A-frags direct from global (no reuse), 3 barriers total (was 13),
//    128 rows x 8 waves per block, 1 block/CU.
//  - qkv/attn/setup kernels unchanged from round 5.

#define QKV_PART 26542080   // 960*6*144*32 elements per q/k/v part

typedef __attribute__((ext_vector_type(8))) short bfrag;          // 8 bf16 (4 VGPR)
typedef __attribute__((ext_vector_type(4))) float f32x4;          // C/D frag
typedef __attribute__((ext_vector_type(4))) unsigned short us4;   // 8B of bf16
typedef __attribute__((ext_vector_type(8))) unsigned short us8;   // 16B of bf16

__device__ __forceinline__ unsigned short f2bf(float f) {
    unsigned int u = __builtin_bit_cast(unsigned int, f);
    u += 0x7fffu + ((u >> 16) & 1u);        // RNE
    return (unsigned short)(u >> 16);
}
__device__ __forceinline__ float bf2f(unsigned short s) {
    return __builtin_bit_cast(float, ((unsigned int)s) << 16);
}
__device__ __forceinline__ int token_of(int iw, int n) {
    int wi = iw % 15, hi = (iw / 15) % 16, zi = iw / 240;
    int ww = n % 12, hh = (n / 12) % 6, zz = n / 72;
    return ((zi * 2 + zz) * 96 + hi * 6 + hh) * 180 + wi * 12 + ww;
}

// ---- setup: transpose+convert w_qkv [192][576] -> [576][192] bf16 ----
__global__ __launch_bounds__(256) void wconv(const float* __restrict__ w_qkv,
                                             unsigned short* __restrict__ wt) {
    int id = blockIdx.x * 256 + threadIdx.x;       // 110592
    if (id >= 110592) return;
    int k = id / 576, c = id - k * 576;
    wt[c * 192 + k] = f2bf(w_qkv[id]);
}

// ---- setup: x fp32 -> bf16 ----
__global__ __launch_bounds__(256) void xconv(const float* __restrict__ x,
                                             unsigned short* __restrict__ x_bf) {
    int id = blockIdx.x * 256 + threadIdx.x;       // 3,317,760 (x8 elems)
    if (id >= 3317760) return;
    const float* xp = x + (size_t)id * 8;
    float4 v0 = *(const float4*)xp;
    float4 v1 = *(const float4*)(xp + 4);
    us8 o;
    o[0] = f2bf(v0.x); o[1] = f2bf(v0.y); o[2] = f2bf(v0.z); o[3] = f2bf(v0.w);
    o[4] = f2bf(v1.x); o[5] = f2bf(v1.y); o[6] = f2bf(v1.z); o[7] = f2bf(v1.w);
    *(us8*)&x_bf[(size_t)id * 8] = o;
}

// ---- setup: transpose+convert w (192x192) -> [n][k] bf16; y=0: w_proj, y=1: w_mlp ----
__global__ __launch_bounds__(256) void wconv2(const float* __restrict__ w_proj,
                                              const float* __restrict__ w_mlp,
                                              unsigned short* __restrict__ wp_t,
                                              unsigned short* __restrict__ wm_t) {
    int id = blockIdx.x * 256 + threadIdx.x;       // 36864
    if (id >= 36864) return;
    const float* src = blockIdx.y ? w_mlp : w_proj;
    unsigned short* dst = blockIdx.y ? wm_t : wp_t;
    int n = id / 192, k = id - n * 192;
    dst[id] = f2bf(src[(size_t)k * 192 + n]);
}

// ---- bias_r[th][i][j] = bias_table[posidx(i,j)][t][h] (bf16) ----
__global__ __launch_bounds__(256) void bias_reorg(const float* __restrict__ bias_table,
                                                  unsigned short* __restrict__ bias_r) {
    __shared__ unsigned short T[384][68];
    int p0 = blockIdx.x * 64;                      // 324 blocks x 64 pairs
    int tid = threadIdx.x;
    for (int e = tid; e < 64 * 384; e += 256) {
        int pl = e / 384, th = e - pl * 384;
        int pair = p0 + pl;
        int i = pair / 144, j = pair - i * 144;
        int z1 = i / 72, h1 = (i / 12) % 6, w1 = i % 12;
        int z2 = j / 72, h2 = (j / 12) % 6, w2 = j % 12;
        int idx = (z1 + 2 * z2) * 828 + (h1 + 6 * h2) * 23 + (w1 - w2 + 11);
        T[th][pl] = f2bf(bias_table[(size_t)idx * 384 + th]);
    }
    __syncthreads();
    for (int e = tid; e < 384 * 16; e += 256) {
        int th = e >> 4, pc = e & 15;
        *(us4*)&bias_r[(size_t)th * 20736 + p0 + pc * 4] = *(const us4*)&T[th][pc * 4];
    }
}

// ---- QKV GEMM, swapped operands: D[c][t] = sum_k W[k][c] x[t][k]. ----
__global__ __launch_bounds__(256) void qkv_mfma(const unsigned short* __restrict__ x_bf,
                                                const unsigned short* __restrict__ wt,
                                                const float* __restrict__ b_qkv,
                                                unsigned short* __restrict__ qkv_ws) {
    int tid = threadIdx.x;
    int m0 = blockIdx.x * 64;
    int w = tid >> 6, l = tid & 63, li = l & 15, lg = l >> 4;
    int nw0 = w * 144;

    f32x4 acc[9][4];
#pragma unroll
    for (int bn = 0; bn < 9; ++bn)
#pragma unroll
        for (int am = 0; am < 4; ++am) acc[bn][am] = (f32x4){0.f, 0.f, 0.f, 0.f};

    for (int kk = 0; kk < 6; ++kk) {
        int k0 = kk * 32 + lg * 8;
        bfrag af[9];
#pragma unroll
        for (int bn = 0; bn < 9; ++bn)
            af[bn] = *(const bfrag*)&wt[(size_t)(nw0 + bn * 16 + li) * 192 + k0];
        bfrag xf[4];
#pragma unroll
        for (int am = 0; am < 4; ++am)
            xf[am] = *(const bfrag*)&x_bf[(size_t)(m0 + am * 16 + li) * 192 + k0];
#pragma unroll
        for (int bn = 0; bn < 9; ++bn)
#pragma unroll
            for (int am = 0; am < 4; ++am)
                acc[bn][am] = __builtin_amdgcn_mfma_f32_16x16x32_bf16(af[bn], xf[am], acc[bn][am], 0, 0, 0);
    }

    int base[4];
#pragma unroll
    for (int am = 0; am < 4; ++am) {
        int t = m0 + am * 16 + li;
        int z = t / 17280; int r1 = t - z * 17280;
        int hh_ = r1 / 180;  int ww_ = r1 - hh_ * 180;
        int zi = z >> 1, zz = z & 1;
        int hi = hh_ / 6, hs = hh_ - hi * 6;
        int wi = ww_ / 12, wsm = ww_ - wi * 12;
        int iw = (zi * 16 + hi) * 15 + wi;
        int n = (zz * 6 + hs) * 12 + wsm;
        base[am] = iw * 27648 + n * 32;
    }
#pragma unroll
    for (int bn = 0; bn < 9; ++bn) {
        int c0 = nw0 + bn * 16 + lg * 4;
        int p = c0 / 192;
        int rem = c0 - p * 192;
        int h = rem >> 5, d = rem & 31;
        float4 bq = *(const float4*)&b_qkv[c0];
        size_t off = (size_t)p * QKV_PART + h * 4608 + d;
#pragma unroll
        for (int am = 0; am < 4; ++am) {
            us4 o;
            o[0] = f2bf(acc[bn][am][0] + bq.x);
            o[1] = f2bf(acc[bn][am][1] + bq.y);
            o[2] = f2bf(acc[bn][am][2] + bq.z);
            o[3] = f2bf(acc[bn][am][3] + bq.w);
            *(us4*)&qkv_ws[off + base[am]] = o;
        }
    }
}

// ---- Attention: block=(iw,h), 3 waves x 3 query-tiles. S^T = mfma(K,Q). ----
__global__ __launch_bounds__(192) void attn_mfma(const unsigned short* __restrict__ qkv_ws,
                                                 const unsigned short* __restrict__ bias_r,
                                                 unsigned short* __restrict__ o_ws) {
    __shared__ __align__(16) unsigned short Kl[144 * 40];   // 11520 B
    __shared__ __align__(16) unsigned short Ql[144 * 40];   // 11520 B (+ aliased Pb)
    __shared__ __align__(16) unsigned short Vt[32 * 168];   // 10752 B (V^T, k-pad to 160)
    int tid = threadIdx.x;
    int iw = blockIdx.x, h = blockIdx.y;
    int w = tid >> 6, l = tid & 63, li = l & 15, lg = l >> 4;

    const unsigned short* qp = qkv_ws + (size_t)(iw * 6 + h) * 4608;
    const unsigned short* kp = qp + (size_t)QKV_PART;
    const unsigned short* vp = qp + 2 * (size_t)QKV_PART;

#pragma unroll
    for (int i = 0; i < 3; ++i) {
        int idx = tid + i * 192;                    // exactly 576
        int r = idx >> 2, g = idx & 3;
        *(uint4*)&Kl[r * 40 + g * 8] = *(const uint4*)&kp[r * 32 + g * 8];
        *(uint4*)&Ql[r * 40 + g * 8] = *(const uint4*)&qp[r * 32 + g * 8];
        uint4 v = *(const uint4*)&vp[r * 32 + g * 8];
        unsigned int vv[4] = {v.x, v.y, v.z, v.w};
#pragma unroll
        for (int e = 0; e < 4; ++e) {
            Vt[(g * 8 + 2 * e + 0) * 168 + r] = (unsigned short)(vv[e] & 0xffffu);
            Vt[(g * 8 + 2 * e + 1) * 168 + r] = (unsigned short)(vv[e] >> 16);
        }
    }
    if (tid < 64) {
        int d = tid >> 1, half = tid & 1;
        *(uint4*)&Vt[d * 168 + 144 + half * 8] = (uint4){0u, 0u, 0u, 0u};
    }
    __syncthreads();

    int it0 = w * 3;
    unsigned short* Pbw = &Ql[(size_t)w * 48 * 40];   // alias: own wave's Q rows
    bfrag qf[3];
#pragma unroll
    for (int itl = 0; itl < 3; ++itl)
        qf[itl] = *(const bfrag*)&Ql[((it0 + itl) * 16 + li) * 40 + lg * 8];

    f32x4 S[9][3];
#pragma unroll
    for (int jt = 0; jt < 9; ++jt) {
        bfrag kf = *(const bfrag*)&Kl[(jt * 16 + li) * 40 + lg * 8];
#pragma unroll
        for (int itl = 0; itl < 3; ++itl) {
            f32x4 z = (f32x4){0.f, 0.f, 0.f, 0.f};
            S[jt][itl] = __builtin_amdgcn_mfma_f32_16x16x32_bf16(kf, qf[itl], z, 0, 0, 0);
        }
    }

    const unsigned short* bp = bias_r + ((size_t)((iw & 63) * 6 + h)) * 20736;
    const float inv_scale = 0.17677669529663687f;   // 1/sqrt(32)
#pragma unroll
    for (int jt = 0; jt < 9; ++jt) {
#pragma unroll
        for (int itl = 0; itl < 3; ++itl) {
            int i = (it0 + itl) * 16 + li;
            int j0 = jt * 16 + lg * 4;
            us4 bv = *(const us4*)&bp[i * 144 + j0];
#pragma unroll
            for (int r = 0; r < 4; ++r)
                S[jt][itl][r] = S[jt][itl][r] * inv_scale + bf2f(bv[r]);
        }
    }

    float inv[3];
#pragma unroll
    for (int itl = 0; itl < 3; ++itl) {
        float mx = -3.0e38f;
#pragma unroll
        for (int jt = 0; jt < 9; ++jt)
#pragma unroll
            for (int r = 0; r < 4; ++r) mx = fmaxf(mx, S[jt][itl][r]);
        mx = fmaxf(mx, __shfl_xor(mx, 16));
        mx = fmaxf(mx, __shfl_xor(mx, 32));
        float sum = 0.f;
#pragma unroll
        for (int jt = 0; jt < 9; ++jt)
#pragma unroll
            for (int r = 0; r < 4; ++r) {
                float e = __expf(S[jt][itl][r] - mx);
                S[jt][itl][r] = e;
                sum += e;
            }
        sum += __shfl_xor(sum, 16);
        sum += __shfl_xor(sum, 32);
        inv[itl] = 1.f / sum;
    }

    f32x4 O[2][3];
#pragma unroll
    for (int dt = 0; dt < 2; ++dt)
#pragma unroll
        for (int itl = 0; itl < 3; ++itl) O[dt][itl] = (f32x4){0.f, 0.f, 0.f, 0.f};

    for (int jc = 0; jc < 5; ++jc) {
#pragma unroll
        for (int itl = 0; itl < 3; ++itl) {
            int irow = itl * 16 + li;
#pragma unroll
            for (int half = 0; half < 2; ++half) {
                int jt = jc * 2 + half;
                us4 pk;
                if (jt < 9) {
                    pk[0] = f2bf(S[jt][itl][0]); pk[1] = f2bf(S[jt][itl][1]);
                    pk[2] = f2bf(S[jt][itl][2]); pk[3] = f2bf(S[jt][itl][3]);
                } else {
                    pk = (us4){0, 0, 0, 0};
                }
                *(us4*)&Pbw[irow * 40 + half * 16 + lg * 4] = pk;
            }
        }
        bfrag pf[3], af[2];
#pragma unroll
        for (int itl = 0; itl < 3; ++itl)
            pf[itl] = *(const bfrag*)&Pbw[(itl * 16 + li) * 40 + lg * 8];
#pragma unroll
        for (int dt = 0; dt < 2; ++dt)
            af[dt] = *(const bfrag*)&Vt[(dt * 16 + li) * 168 + jc * 32 + lg * 8];
#pragma unroll
        for (int dt = 0; dt < 2; ++dt)
#pragma unroll
            for (int itl = 0; itl < 3; ++itl)
                O[dt][itl] = __builtin_amdgcn_mfma_f32_16x16x32_bf16(af[dt], pf[itl], O[dt][itl], 0, 0, 0);
    }

#pragma unroll
    for (int itl = 0; itl < 3; ++itl) {
#pragma unroll
        for (int dt = 0; dt < 2; ++dt) {
            us4 ov;
            ov[0] = f2bf(O[dt][itl][0] * inv[itl]);
            ov[1] = f2bf(O[dt][itl][1] * inv[itl]);
            ov[2] = f2bf(O[dt][itl][2] * inv[itl]);
            ov[3] = f2bf(O[dt][itl][3] * inv[itl]);
            *(us4*)&Pbw[(itl * 16 + li) * 40 + dt * 16 + lg * 4] = ov;
        }
    }
#pragma unroll
    for (int s = 0; s < 3; ++s) {
        int gi = s * 64 + l;
        int row = gi >> 2, g = gi & 3;
        uint4 v = *(const uint4*)&Pbw[row * 40 + g * 8];
        int t = token_of(iw, it0 * 16 + row);
        *(uint4*)&o_ws[(size_t)t * 192 + h * 32 + g * 8] = v;
    }
}

// ---- Fused proj+LN1+res -> mlp+LN2+res. 128 rows/block, 8 waves.
// Whole weight matrix in LDS per GEMM (72 KB, staged once); GEMM1 A-frags
// direct from global (o rows have no reuse). 3 barriers total. ----
__global__ __launch_bounds__(512) void mlp_mfma(const unsigned short* __restrict__ o_ws,
                                                const float* __restrict__ x,
                                                const unsigned short* __restrict__ wp_t,
                                                const float* __restrict__ b_proj,
                                                const float* __restrict__ g1,
                                                const float* __restrict__ b1,
                                                const float* __restrict__ g2,
                                                const float* __restrict__ b2,
                                                const unsigned short* __restrict__ wm_t,
                                                const float* __restrict__ b_mlp,
                                                float* __restrict__ out) {
    __shared__ __align__(16) unsigned short Al[128 * 200];  // 51200 B (x1 bf16)
    __shared__ __align__(16) unsigned short Bf[192 * 200];  // 76800 B (full weight [n][k])
    int tid = threadIdx.x;
    int t0 = blockIdx.x * 128;
    int w = tid >> 6, l = tid & 63, li = l & 15, lg = l >> 4;

    // stage Bf = wp_t (192x192): 4608 uint4 / 512 threads = 9 each
#pragma unroll
    for (int i = 0; i < 9; ++i) {
        int idx = tid + i * 512;                 // < 4608
        int r = idx / 24, g = idx - r * 24;
        *(uint4*)&Bf[r * 200 + g * 8] = *(const uint4*)&wp_t[(size_t)r * 192 + g * 8];
    }
    __syncthreads();

    // GEMM1: rows w*16..+15 (A direct from global), all 192 cols, K=192, no barriers
    f32x4 C[12];
#pragma unroll
    for (int nt = 0; nt < 12; ++nt) C[nt] = (f32x4){0.f, 0.f, 0.f, 0.f};
    for (int kk = 0; kk < 6; ++kk) {
        int k0 = kk * 32 + lg * 8;
        bfrag a = *(const bfrag*)&o_ws[(size_t)(t0 + w * 16 + li) * 192 + k0];
#pragma unroll
        for (int nt = 0; nt < 12; ++nt) {
            bfrag b = *(const bfrag*)&Bf[(nt * 16 + li) * 200 + k0];
            C[nt] = __builtin_amdgcn_mfma_f32_16x16x32_bf16(a, b, C[nt], 0, 0, 0);
        }
    }
    __syncthreads();                             // all waves done reading Bf(wp)

    // restage Bf = wm_t; its latency hides under the LN1 VALU phase below
#pragma unroll
    for (int i = 0; i < 9; ++i) {
        int idx = tid + i * 512;
        int r = idx / 24, g = idx - r * 24;
        *(uint4*)&Bf[r * 200 + g * 8] = *(const uint4*)&wm_t[(size_t)r * 192 + g * 8];
    }

    // LN1 + residual; C := x1 (f32); write bf16 x1 into Al (own wave's rows)
    {
        float bp[12], gg[12], bb[12];
#pragma unroll
        for (int nt = 0; nt < 12; ++nt) {
            int f = nt * 16 + li;
            bp[nt] = b_proj[f]; gg[nt] = g1[f]; bb[nt] = b1[f];
        }
#pragma unroll
        for (int r = 0; r < 4; ++r) {
            float s1 = 0.f;
#pragma unroll
            for (int nt = 0; nt < 12; ++nt) s1 += C[nt][r] + bp[nt];
            s1 += __shfl_xor(s1, 1); s1 += __shfl_xor(s1, 2);
            s1 += __shfl_xor(s1, 4); s1 += __shfl_xor(s1, 8);
            float mean = s1 * (1.f / 192.f);
            float s2 = 0.f;
#pragma unroll
            for (int nt = 0; nt < 12; ++nt) {
                float dv = C[nt][r] + bp[nt] - mean; s2 += dv * dv;
            }
            s2 += __shfl_xor(s2, 1); s2 += __shfl_xor(s2, 2);
            s2 += __shfl_xor(s2, 4); s2 += __shfl_xor(s2, 8);
            float rstd = rsqrtf(s2 * (1.f / 192.f) + 1e-5f);
            int row = w * 16 + lg * 4 + r;
            int t = t0 + row;
#pragma unroll
            for (int nt = 0; nt < 12; ++nt) {
                int f = nt * 16 + li;
                float ln = (C[nt][r] + bp[nt] - mean) * rstd * gg[nt] + bb[nt];
                float x1 = x[(size_t)t * 192 + f] + ln;
                C[nt][r] = x1;
                Al[row * 200 + f] = f2bf(x1);
            }
        }
    }
    __syncthreads();                             // Bf(wm) staged; Al x1 ready

    // GEMM2: x1 @ w_mlp (A from Al own rows, B from Bf), no barriers
    f32x4 C2[12];
#pragma unroll
    for (int nt = 0; nt < 12; ++nt) C2[nt] = (f32x4){0.f, 0.f, 0.f, 0.f};
    for (int kk = 0; kk < 6; ++kk) {
        int k0 = kk * 32 + lg * 8;
        bfrag a = *(const bfrag*)&Al[(w * 16 + li) * 200 + k0];
#pragma unroll
        for (int nt = 0; nt < 12; ++nt) {
            bfrag b = *(const bfrag*)&Bf[(nt * 16 + li) * 200 + k0];
            C2[nt] = __builtin_amdgcn_mfma_f32_16x16x32_bf16(a, b, C2[nt], 0, 0, 0);
        }
    }

    // LN2 + residual -> out (fp32)
    {
        float bp[12], gg[12], bb[12];
#pragma unroll
        for (int nt = 0; nt < 12; ++nt) {
            int f = nt * 16 + li;
            bp[nt] = b_mlp[f]; gg[nt] = g2[f]; bb[nt] = b2[f];
        }
#pragma unroll
        for (int r = 0; r < 4; ++r) {
            float s1 = 0.f;
#pragma unroll
            for (int nt = 0; nt < 12; ++nt) s1 += C2[nt][r] + bp[nt];
            s1 += __shfl_xor(s1, 1); s1 += __shfl_xor(s1, 2);
            s1 += __shfl_xor(s1, 4); s1 += __shfl_xor(s1, 8);
            float mean = s1 * (1.f / 192.f);
            float s2 = 0.f;
#pragma unroll
            for (int nt = 0; nt < 12; ++nt) {
                float dv = C2[nt][r] + bp[nt] - mean; s2 += dv * dv;
            }
            s2 += __shfl_xor(s2, 1); s2 += __shfl_xor(s2, 2);
            s2 += __shfl_xor(s2, 4); s2 += __shfl_xor(s2, 8);
            float rstd = rsqrtf(s2 * (1.f / 192.f) + 1e-5f);
            int t = t0 + w * 16 + lg * 4 + r;
#pragma unroll
            for (int nt = 0; nt < 12; ++nt) {
                int f = nt * 16 + li;
                float ln = (C2[nt][r] + bp[nt] - mean) * rstd * gg[nt] + bb[nt];
                out[(size_t)t * 192 + f] = C[nt][r] + ln;
            }
        }
    }
}

extern "C" void kernel_launch(void* const* d_in, const int* in_sizes, int n_in,
                              void* d_out, int out_size, void* d_ws, size_t ws_size,
                              hipStream_t stream) {
    const float* x          = (const float*)d_in[0];
    const float* w_qkv      = (const float*)d_in[1];
    const float* b_qkv      = (const float*)d_in[2];
    const float* w_proj     = (const float*)d_in[3];
    const float* b_proj     = (const float*)d_in[4];
    const float* bias_table = (const float*)d_in[5];
    const float* g1         = (const float*)d_in[6];
    const float* b1         = (const float*)d_in[7];
    const float* g2         = (const float*)d_in[8];
    const float* b2         = (const float*)d_in[9];
    const float* w_mlp      = (const float*)d_in[10];
    const float* b_mlp      = (const float*)d_in[11];

    char* ws = (char*)d_ws;
    unsigned short* qkv_ws = (unsigned short*)ws;                   // 159,252,480 B
    unsigned short* bias_r = (unsigned short*)(ws + 159252480);     //  15,925,248 B
    unsigned short* o_ws   = (unsigned short*)(ws + 175177728);     //  53,084,160 B
    // Overlays (stream-order checked):
    //  w_t  @ bias_r : wconv -> qkv read -> bias_reorg clobber (after qkv)
    //  x_bf @ o_ws   : xconv -> qkv read -> attn clobber (after qkv)
    //  wp_t/wm_t @ qkv_ws : wconv2 (after attn) -> mlp read
    unsigned short* w_t    = bias_r;                                //     221,184 B
    unsigned short* x_bf   = o_ws;                                  //  53,084,160 B
    unsigned short* wp_t   = qkv_ws;                                //     147,456 B
    unsigned short* wm_t   = qkv_ws + 73728;                        //     147,456 B

    wconv<<<432, 256, 0, stream>>>(w_qkv, w_t);
    xconv<<<12960, 256, 0, stream>>>(x, x_bf);
    qkv_mfma<<<2160, 256, 0, stream>>>(x_bf, w_t, b_qkv, qkv_ws);
    bias_reorg<<<324, 256, 0, stream>>>(bias_table, bias_r);
    attn_mfma<<<dim3(960, 6), 192, 0, stream>>>(qkv_ws, bias_r, o_ws);
    wconv2<<<dim3(144, 2), 256, 0, stream>>>(w_proj, w_mlp, wp_t, wm_t);
    mlp_mfma<<<1080, 512, 0, stream>>>(o_ws, x, wp_t, b_proj, g1, b1, g2, b2,
                                       wm_t, b_mlp, (float*)d_out);
}